// Round 2
// baseline (533.020 us; speedup 1.0000x reference)
//
#include <hip/hip_runtime.h>
#include <hip/hip_bf16.h>

typedef unsigned short u16;
typedef __attribute__((ext_vector_type(8))) __bf16 bf16x8;
typedef __attribute__((ext_vector_type(4))) float f32x4;

#define DIN 4096
#define DOUT 4096
#define MROWS 8192

__device__ __forceinline__ u16 f2bf(float f) {
  unsigned int u = __float_as_uint(f);
  u += 0x7fffu + ((u >> 16) & 1u);   // RNE; inputs are finite randoms
  return (u16)(u >> 16);
}

__device__ __forceinline__ void gl2lds16(const void* g, void* l) {
  __builtin_amdgcn_global_load_lds(
      (const __attribute__((address_space(1))) unsigned int*)g,
      (__attribute__((address_space(3))) unsigned int*)l, 16, 0, 0);
}

// ---------------------------------------------------------------------------
// Kernel 1: fused prep. Grid-stride casts of x and W (exact trip counts,
// unrolled x4 for load ILP), plus convu transpose and Wt pack.
// Launch: 2048 blocks x 256 -> NT = 524288 threads.
//   x:  8388608 float4  (16 iters/thread)
//   W:  4194304 float4  ( 8 iters/thread)
__global__ __launch_bounds__(256) void prep_all(
    const float* __restrict__ x, const float* __restrict__ W,
    const float* __restrict__ up, const float* __restrict__ route,
    const float* __restrict__ down,
    u16* __restrict__ Xb, u16* __restrict__ Wb,
    u16* __restrict__ Ub, u16* __restrict__ Wt) {
  const size_t NT = 2048 * 256;
  const size_t gtid = (size_t)blockIdx.x * 256 + threadIdx.x;

  // --- small region A: Ub[n][c] = bf16(up_flat[c][n]), c<32 (transpose) ---
  if (gtid < 4096) {
    const int n = (int)gtid;
    union { u16 us[32]; uint4 q[4]; } o;
    #pragma unroll
    for (int c = 0; c < 32; ++c) o.us[c] = f2bf(up[(size_t)c * DOUT + n]);
    uint4* dst = (uint4*)(Ub + (size_t)n * 32);
    #pragma unroll
    for (int q = 0; q < 4; ++q) dst[q] = o.q[q];
  }

  // --- small region B: Wt[48][4096] pack (route col / down col / zero) ---
  if (gtid < 49152) {
    const int c = (int)(gtid >> 10);
    const int k0 = ((int)gtid & 1023) * 4;
    const float* route3 = route + 3 * DIN * 5;  // lora_route[3]
    float v[4];
    #pragma unroll
    for (int j = 0; j < 4; ++j) {
      int k = k0 + j;
      float f;
      if (c < 3)       f = route3[(size_t)k * 5 + c];
      else if (c < 35) f = down[(size_t)((c - 3) >> 3) * DIN * 8 + (size_t)k * 8 + ((c - 3) & 7)];
      else             f = 0.f;
      v[j] = f;
    }
    ushort4 o;
    o.x = f2bf(v[0]); o.y = f2bf(v[1]); o.z = f2bf(v[2]); o.w = f2bf(v[3]);
    *(ushort4*)(Wt + (size_t)c * DIN + k0) = o;
  }

  // --- stream region C: x fp32 -> bf16 (33554432 floats) ---
  #pragma unroll 4
  for (int it = 0; it < 16; ++it) {
    size_t i = gtid + (size_t)it * NT;
    float4 v = ((const float4*)x)[i];
    ushort4 o;
    o.x = f2bf(v.x); o.y = f2bf(v.y); o.z = f2bf(v.z); o.w = f2bf(v.w);
    ((ushort4*)Xb)[i] = o;
  }

  // --- stream region D: W fp32 -> bf16 (16777216 floats) ---
  #pragma unroll 4
  for (int it = 0; it < 8; ++it) {
    size_t i = gtid + (size_t)it * NT;
    float4 v = ((const float4*)W)[i];
    ushort4 o;
    o.x = f2bf(v.x); o.y = f2bf(v.y); o.z = f2bf(v.z); o.w = f2bf(v.w);
    ((ushort4*)Wb)[i] = o;
  }
}

// ---------------------------------------------------------------------------
// Kernel 2: MFMA tall-skinny GEMM Pw[split][8192][48] = Xb . Wt^T over K-slice.
// BM=64 (was 128): grid (128,8) = 1024 blocks -> 4 blocks/CU, 16 waves/CU so
// barrier drains hide under other resident blocks. LDS 14 KiB.
// Same K-summation order as before -> bit-identical Pw.
__global__ __launch_bounds__(256) void coeffgemm(
    const u16* __restrict__ Xb, const u16* __restrict__ Wt,
    float* __restrict__ Pw) {
  __shared__ __align__(16) u16 As[64 * 64];
  __shared__ __align__(16) u16 Bs[48 * 64];
  const int tid = threadIdx.x;
  const int m0 = blockIdx.x * 64;
  const int kb = blockIdx.y * 512;
  const int lane = tid & 63;
  const int w = tid >> 6;
  const int wr = w * 16;            // wave's 16 rows
  const int fm = lane & 15;
  const int xr = fm & 7;
  const int qd = lane >> 4;

  f32x4 acc[3];
  #pragma unroll
  for (int j = 0; j < 3; ++j) acc[j] = (f32x4){0.f, 0.f, 0.f, 0.f};

  // staging: chunk L -> lrow=L>>3, c'=L&7, src col chunk c=c'^(lrow&7).
  // Thread t stages A chunks t and t+256 (row +32: same c since 32%8==0),
  // B chunk t, and (t<128) B chunk 256+t (row +32, same c).
  const int arow = tid >> 3;
  const int ac = ((tid & 7) ^ (arow & 7)) * 8;
  const u16* gA = Xb + (size_t)(m0 + arow) * DIN + kb + ac;
  const u16* gBt = Wt + (size_t)arow * DIN + kb + ac;

  for (int kc = 0; kc < 512; kc += 64) {
    gl2lds16(gBt + kc, Bs + tid * 8);
    if (tid < 128)
      gl2lds16(gBt + 32 * DIN + kc, Bs + (256 + tid) * 8);
    gl2lds16(gA + kc, As + tid * 8);
    gl2lds16(gA + 32 * DIN + kc, As + (256 + tid) * 8);
    __syncthreads();
    #pragma unroll
    for (int kk = 0; kk < 64; kk += 32) {
      const int q = (kk >> 3) + qd;
      bf16x8 af = *(const bf16x8*)(As + (wr + fm) * 64 + ((q ^ xr) << 3));
      bf16x8 bfr[3];
      #pragma unroll
      for (int j = 0; j < 3; ++j)
        bfr[j] = *(const bf16x8*)(Bs + (j * 16 + fm) * 64 + ((q ^ xr) << 3));
      #pragma unroll
      for (int j = 0; j < 3; ++j)
        acc[j] = __builtin_amdgcn_mfma_f32_16x16x32_bf16(af, bfr[j], acc[j], 0, 0, 0);
    }
    __syncthreads();
  }
  const int em = (lane >> 4) * 4;
  const int en = lane & 15;
  const size_t pbase = (size_t)blockIdx.y * MROWS;
  #pragma unroll
  for (int j = 0; j < 3; ++j)
    #pragma unroll
    for (int r = 0; r < 4; ++r)
      Pw[(pbase + m0 + wr + em + r) * 48 + j * 16 + en] = acc[j][r];
}

// ---------------------------------------------------------------------------
// Kernel 3: reduce 8 K-split partials, softmax gate, emit Cb[8192][32] bf16.
// 128 blocks (was 32). Thread = (row rl=tid>>2, colgroup cg=tid&3 of 12 cols):
// wave reads are 3072-B contiguous. Logits (cols 0..2) live in cg0's s[0..2];
// broadcast via __shfl within each 4-lane row group. Per-column accumulation
// order identical to before -> bit-identical Cb.
__global__ __launch_bounds__(256) void reduce_coeff(const float* __restrict__ Pw,
                                                    u16* __restrict__ Cb) {
  const int tid = threadIdx.x;
  const int rl = tid >> 2;
  const int cg = tid & 3;
  const int m = blockIdx.x * 64 + rl;
  const int lane = tid & 63;

  float s[12];
  #pragma unroll
  for (int q = 0; q < 12; ++q) s[q] = 0.f;
  for (int sp = 0; sp < 8; ++sp) {
    const float4* p = (const float4*)(Pw + ((size_t)sp * MROWS + m) * 48 + cg * 12);
    #pragma unroll
    for (int q = 0; q < 3; ++q) {
      float4 v = p[q];
      s[q * 4 + 0] += v.x; s[q * 4 + 1] += v.y;
      s[q * 4 + 2] += v.z; s[q * 4 + 3] += v.w;
    }
  }
  // broadcast logits (global cols 0..2 = cg0's s[0..2]) to the row's 4 lanes
  const int src = lane & ~3;
  const float L0 = __shfl(s[0], src);
  const float L1 = __shfl(s[1], src);
  const float L2 = __shfl(s[2], src);
  const float mx = fmaxf(L0, fmaxf(L1, L2));
  const float e0 = __expf(L0 - mx), e1 = __expf(L1 - mx), e2 = __expf(L2 - mx);
  const float inv = 1.f / (e0 + e1 + e2);
  const float om0 = e0 * inv, om1 = e1 * inv, om2 = e2 * inv;
  #pragma unroll
  for (int j = 0; j < 12; ++j) {
    const int G = cg * 12 + j;          // global col in [0,48)
    if (G >= 3 && G < 35) {             // output col c = G-3 in [0,32)
      const float wgt = (G < 11) ? om0 : (G < 19) ? om1 : (G < 27) ? om2 : 1.f;
      Cb[(size_t)m * 32 + (G - 3)] = f2bf(s[j] * wgt);
    }
  }
}

// ---------------------------------------------------------------------------
// Kernel 4: out = Xb @ Wb^T + Cb @ Ub^T.  (unchanged from round 1)
// 256x256 tile, BK=64, 512 threads (8 waves: 2M x 4N), 8-phase schedule,
// counted vmcnt(4), XOR-swizzled packed LDS, setprio around MFMA clusters.

#define MF(a, b, c) __builtin_amdgcn_mfma_f32_16x16x32_bf16(a, b, c, 0, 0, 0)

#define MROW(A, I) \
  acc[I][0] = MF(A, bfr0, acc[I][0]); \
  acc[I][1] = MF(A, bfr1, acc[I][1]); \
  acc[I][2] = MF(A, bfr2, acc[I][2]); \
  acc[I][3] = MF(A, bfr3, acc[I][3]);

#define VM4 asm volatile("s_waitcnt vmcnt(4)" ::: "memory")
#define VM0 asm volatile("s_waitcnt vmcnt(0)" ::: "memory")

#define STA(REG, KOFF) { const u16* s_ = gA + (KOFF); \
  gl2lds16(s_, dA + (REG) * 8192); \
  gl2lds16(s_ + 128 * 4096, dA + (REG) * 8192 + 4096); }
#define STB(REG, KOFF) { const u16* s_ = gB + (KOFF); \
  gl2lds16(s_, dB + (REG) * 8192); \
  gl2lds16(s_ + 128 * 4096, dB + (REG) * 8192 + 4096); }
#define STC { const u16* s_ = Cb + (size_t)(m0 + gr1) * 32 + kc1; \
  gl2lds16(s_, dA); gl2lds16(s_ + 128 * 32, dA + 4096); }
#define STU { const u16* s_ = Ub + (size_t)(n0 + gr1) * 32 + kc1; \
  gl2lds16(s_, dB); gl2lds16(s_ + 128 * 32, dB + 4096); }

#define PH(REG, IH, LOADB, ISSUE, VMX) { \
  const u16* ap_ = sm + (REG) * 8192 + wmoff + (IH) * 2048 + off0; \
  bf16x8 af0 = *(const bf16x8*)(ap_); \
  bf16x8 af1 = *(const bf16x8*)(ap_ + 512); \
  bf16x8 af2 = *(const bf16x8*)(ap_ + 1024); \
  bf16x8 af3 = *(const bf16x8*)(ap_ + 1536); \
  if (LOADB) { \
    const u16* bp_ = sm + 32768 + (REG) * 8192 + wnoff + off0; \
    bfr0 = *(const bf16x8*)(bp_); \
    bfr1 = *(const bf16x8*)(bp_ + 512); \
    bfr2 = *(const bf16x8*)(bp_ + 1024); \
    bfr3 = *(const bf16x8*)(bp_ + 1536); \
  } \
  ISSUE; \
  asm volatile("" ::: "memory"); \
  __builtin_amdgcn_s_barrier(); \
  __builtin_amdgcn_s_setprio(1); \
  MROW(af0, (IH) * 4 + 0) \
  MROW(af1, (IH) * 4 + 1) \
  MROW(af2, (IH) * 4 + 2) \
  MROW(af3, (IH) * 4 + 3) \
  __builtin_amdgcn_s_setprio(0); \
  VMX; \
  asm volatile("" ::: "memory"); \
  __builtin_amdgcn_s_barrier(); \
}

#define TILE(B, I1, I2, I3, I4, VMX) { \
  bf16x8 bfr0, bfr1, bfr2, bfr3; \
  PH((B) * 2 + 0, 0, 1, I1, (void)0) \
  PH((B) * 2 + 0, 1, 0, I2, (void)0) \
  PH((B) * 2 + 1, 0, 1, I3, (void)0) \
  PH((B) * 2 + 1, 1, 0, I4, VMX) \
}

__global__ __launch_bounds__(512, 2) void gemm_fused8(
    const u16* __restrict__ Xb, const u16* __restrict__ Wb,
    const u16* __restrict__ Cb, const u16* __restrict__ Ub,
    float* __restrict__ out) {
  __shared__ __align__(16) u16 sm[65536];   // 128 KiB: A [0,32768), B [32768,65536)
  const int tid = threadIdx.x;
  const int bid = blockIdx.x;
  const int wg = (bid & 7) * 64 + (bid >> 3);   // XCD swizzle (nwg=512, 8|512)
  const int mt = wg >> 4;                        // 32 M-tiles
  const int nt = wg & 15;                        // 16 N-tiles
  const int m0 = mt * 256;
  const int n0 = nt * 256;
  const int lane = tid & 63;
  const int w = tid >> 6;
  const int wm = w >> 2;        // 0..1  (128 rows each)
  const int wn = w & 3;         // 0..3  (64 cols each)
  const int fm = lane & 15;
  const int qd = lane >> 4;
  const int off0 = (fm >> 1) * 64 + (((((fm & 1) << 2) | qd)) ^ (fm >> 1)) * 8;
  const int wmoff = wm * 4096;
  const int wnoff = wn * 2048;

  const int c1 = (tid & 7) ^ ((tid >> 3) & 7);
  const int gr1 = 2 * (tid >> 3) + (c1 >> 2);
  const int kc1 = (c1 & 3) * 8;
  const u16* gA = Xb + (size_t)(m0 + gr1) * 4096 + kc1;
  const u16* gB = Wb + (size_t)(n0 + gr1) * 4096 + kc1;
  u16* dA = sm + tid * 8;
  u16* dB = sm + 32768 + tid * 8;

  f32x4 acc[8][4];
  #pragma unroll
  for (int i = 0; i < 8; ++i)
    #pragma unroll
    for (int j = 0; j < 4; ++j) acc[i][j] = (f32x4){0.f, 0.f, 0.f, 0.f};

  STA(0, 0)  STB(0, 0)
  STA(1, 32) STB(1, 32)
  STA(2, 64) STB(2, 64)
  VM4;
  asm volatile("" ::: "memory");
  __builtin_amdgcn_s_barrier();

  for (int T = 0; T < 62; T += 2) {
    TILE(0, STA(3, T * 64 + 96),  STB(3, T * 64 + 96),
            STA(0, T * 64 + 128), STB(0, T * 64 + 128), VM4)
    TILE(1, STA(1, T * 64 + 160), STB(1, T * 64 + 160),
            STA(2, T * 64 + 192), STB(2, T * 64 + 192), VM4)
  }
  TILE(0, STA(3, 4064), STB(3, 4064), (void)0, (void)0, VM0)
  TILE(1, STC, STU, (void)0, (void)0, VM0)

  // LoRA K=32 tail from regions A0/B0
  {
    const u16* ap = sm + wmoff + off0;
    const u16* bp = sm + 32768 + wnoff + off0;
    bf16x8 bfr0 = *(const bf16x8*)(bp);
    bf16x8 bfr1 = *(const bf16x8*)(bp + 512);
    bf16x8 bfr2 = *(const bf16x8*)(bp + 1024);
    bf16x8 bfr3 = *(const bf16x8*)(bp + 1536);
    #pragma unroll
    for (int i = 0; i < 8; ++i) {
      bf16x8 a = *(const bf16x8*)(ap + i * 512);
      acc[i][0] = MF(a, bfr0, acc[i][0]);
      acc[i][1] = MF(a, bfr1, acc[i][1]);
      acc[i][2] = MF(a, bfr2, acc[i][2]);
      acc[i][3] = MF(a, bfr3, acc[i][3]);
    }
  }

  const int em = qd * 4;
  const int en = fm;
  const size_t obase = (size_t)(m0 + wm * 128) * DOUT + n0 + wn * 64 + en;
  #pragma unroll
  for (int i = 0; i < 8; ++i)
    #pragma unroll
    for (int j = 0; j < 4; ++j)
      #pragma unroll
      for (int r = 0; r < 4; ++r)
        out[obase + (size_t)(i * 16 + em + r) * DOUT + j * 16] = acc[i][j][r];
}

// ---------------------------------------------------------------------------
extern "C" void kernel_launch(void* const* d_in, const int* in_sizes, int n_in,
                              void* d_out, int out_size, void* d_ws, size_t ws_size,
                              hipStream_t stream) {
  const float* x     = (const float*)d_in[0];  // [4,2048,4096]
  const float* W     = (const float*)d_in[1];  // [4096,4096]
  const float* down  = (const float*)d_in[2];  // [5,4096,8]
  const float* up    = (const float*)d_in[3];  // [5,8,4096]
  const float* route = (const float*)d_in[4];  // [5,4096,5]
  float* out = (float*)d_out;

  char* ws = (char*)d_ws;
  u16*   Xb = (u16*)ws;                        // 64 MiB
  u16*   Wb = (u16*)(ws + 67108864);           // 32 MiB
  u16*   Cb = (u16*)(ws + 100663296);          // 512 KiB
  u16*   Ub = (u16*)(ws + 101187584);          // 256 KiB
  u16*   Wt = (u16*)(ws + 101449728);          // 384 KiB
  float* Pw = (float*)(ws + 101842944);        // 12 MiB

  prep_all<<<2048, 256, 0, stream>>>(x, W, up, route, down, Xb, Wb, Ub, Wt);
  coeffgemm<<<dim3(128, 8), 256, 0, stream>>>(Xb, Wt, Pw);
  reduce_coeff<<<128, 256, 0, stream>>>(Pw, Cb);
  gemm_fused8<<<512, 512, 0, stream>>>(Xb, Wb, Cb, Ub, out);
}